// Round 1
// baseline (1273.591 us; speedup 1.0000x reference)
//
#include <hip/hip_runtime.h>
#include <cmath>

// GaussCRF on MI355X — round 8.
// B=2, C=21, H=W=512, blur=4 -> h=w=128, K=11 (121 shifts), 5 iterations.
//
// r7 post-mortem: combine/init are near their HBM floor (~9 us each, 16
// waves/CU); the pipeline floor is ~70-80 us but we sit at 317 us. msg_k is
// the latency hole: 64-thr blocks = 1 wave, 512 waves total = 2 waves/CU
// (6% occupancy). Each wave serially eats 726 ds_read_b128 + 121 strided g
// loads with nothing to hide the latency behind.
// r8 change: msg_k only. Same 8x8 tile, same [18][18][28] LDS halo, same
// tap order (bit-identical numerics), but 384 threads = 6 waves/block; wave
// w owns channel quad 4w for all 64 positions. Per-lane: 121 taps x (1
// ds_read_b128 + 4 FMA). 12 waves/CU (3/SIMD). The 6 waves read identical g
// addresses ~in lockstep -> L1/L2 absorbs the replication (31 KB g
// slice/block); HBM traffic unchanged.

#define BB 2
#define CC 21
#define HH 512
#define WW 512
#define HP 128
#define WP 128
#define KF 11
#define SPAN 5
#define NB 121
#define NITER 5
#define PLF (HH*WW)
#define PLP (HP*WP)
#define PC 24      // packed channel stride (floats), 96 B = 6 x float4
#define LSTR 28    // LDS channel stride in msg tile (2-way bank aliasing)

__global__ void pool_img_k(const float* __restrict__ img,
                           const float* __restrict__ col_schan,
                           float* __restrict__ cf) {
    int idx = blockIdx.x * blockDim.x + threadIdx.x;
    if (idx >= BB*3*PLP) return;
    int Y  = idx & (WP-1);
    int X  = (idx >> 7) & (HP-1);
    int bc = idx >> 14;
    const float* base = img + ((size_t)bc*HH + X*4)*WW + Y*4;
    float s = 0.f;
    #pragma unroll
    for (int i = 0; i < 4; ++i)
        #pragma unroll
        for (int j = 0; j < 4; ++j)
            s += base[i*WW + j];
    cf[idx] = s * (1.f/16.f) * col_schan[0];
}

// one thread per (b, ij, X, Y); g layout [b][ij][X][Y] fp32
__global__ void gauss_k(const float* __restrict__ cf,
                        const float* __restrict__ pos_sdims,
                        const float* __restrict__ pos_compat,
                        const float* __restrict__ col_compat,
                        float* __restrict__ g) {
    int idx = blockIdx.x * blockDim.x + threadIdx.x;
    if (idx >= BB*NB*PLP) return;
    int xy = idx & (PLP-1);
    int t  = idx >> 14;
    int ij = t % NB;
    int b  = t / NB;
    int Y = xy & (WP-1);
    int X = xy >> 7;
    int di = ij / KF - SPAN;
    int dj = ij % KF - SPAN;
    int Xn = X + di, Yn = Y + dj;
    float val = 0.f;
    if (Xn >= 0 && Xn < HP && Yn >= 0 && Yn < WP) {
        const float* cb = cf + (size_t)b*3*PLP;
        int o0 = xy, o = Xn*WP + Yn;
        float d0 = cb[o]         - cb[o0];
        float d1 = cb[PLP + o]   - cb[PLP + o0];
        float d2 = cb[2*PLP + o] - cb[2*PLP + o0];
        float cd2 = d0*d0 + d1*d1 + d2*d2;
        float ps  = 4.f * pos_sdims[0];
        float pd2 = ps*ps * (float)(di*di + dj*dj);
        val = pos_compat[0] * expf(-0.5f*pd2) + col_compat[0] * expf(-0.5f*cd2);
    }
    g[idx] = val;
}

// p0 = 4x4 pool of log_softmax(unary), packed fp32 [b][X][Y][24].
// grid (16, 32, BB): block covers 16 rows x 32 cols of full-res pixels.
__global__ __launch_bounds__(256) void init_p_k(const float* __restrict__ unary,
                                                float* __restrict__ p) {
    int b = blockIdx.z, tx = blockIdx.y, ty = blockIdx.x;
    int t = threadIdx.x;
    int row = t >> 4, c2 = t & 15;
    int x = tx*16 + row, y = ty*32 + 2*c2;
    size_t base = (size_t)b*CC*PLF + (size_t)x*WW + y;
    float va[CC], vb[CC];
    float ma = -1e30f, mb = -1e30f;
    #pragma unroll
    for (int c = 0; c < CC; ++c) {
        float2 u = *(const float2*)(unary + base + (size_t)c*PLF);
        va[c] = u.x; vb[c] = u.y;
        ma = fmaxf(ma, u.x); mb = fmaxf(mb, u.y);
    }
    float sa = 0.f, sb = 0.f;
    #pragma unroll
    for (int c = 0; c < CC; ++c) { sa += expf(va[c]-ma); sb += expf(vb[c]-mb); }
    float lsa = ma + logf(sa), lsb = mb + logf(sb);
    float out[PC];
    #pragma unroll
    for (int c = 0; c < PC; ++c) out[c] = 0.f;
    #pragma unroll
    for (int c = 0; c < CC; ++c) {
        float sm = (va[c]-lsa) + (vb[c]-lsb);
        sm += __shfl_xor(sm, 1);
        sm += __shfl_xor(sm, 16);
        sm += __shfl_xor(sm, 32);
        out[c] = sm * (1.f/16.f);
    }
    int lane = t & 63;
    if ((lane & 49) == 0) {                  // bits {0,4,5} == 0
        int X = tx*4 + (t >> 6), Y = ty*8 + (c2 >> 1);
        float4* dst = (float4*)(p + ((size_t)(b*HP + X)*WP + Y)*PC);
        const float4* src = (const float4*)out;
        dst[0]=src[0]; dst[1]=src[1]; dst[2]=src[2];
        dst[3]=src[3]; dst[4]=src[4]; dst[5]=src[5];
    }
}

// msg[b,c,X,Y] = sum_ij g[b,ij,X,Y] * p_packed[b,X+di-5,Y+dj-5,c]
// block = 384 thr = 6 waves; wave w owns channel quad 4w for the 8x8
// position tile (lane = position). grid (16,16,BB) = 512 blocks,
// 12 waves/CU. Tap order identical to r7 -> bit-identical accumulation.
__global__ __launch_bounds__(384) void msg_k(const float* __restrict__ g,
                                             const float* __restrict__ p,
                                             float* __restrict__ msg) {
    int b = blockIdx.z, tx = blockIdx.y, ty = blockIdx.x;
    int t = threadIdx.x;
    __shared__ __align__(16) float pt[18*18*LSTR];   // 36.3 KB
    int X0 = tx*8 - SPAN, Y0 = ty*8 - SPAN;
    const float4* pg = (const float4*)(p + (size_t)b*PLP*PC);
    for (int e = t; e < 18*18*6; e += 384) {
        int pos = e / 6, k = e % 6;
        int r = pos / 18, cl = pos % 18;
        int gX = X0 + r, gY = Y0 + cl;
        float4 v = {0.f,0.f,0.f,0.f};
        if (gX >= 0 && gX < HP && gY >= 0 && gY < WP)
            v = pg[(size_t)(gX*WP + gY)*6 + k];
        *(float4*)(pt + pos*LSTR + k*4) = v;
    }
    __syncthreads();
    int w = t >> 6, lane = t & 63;
    int x = lane >> 3, y = lane & 7;
    int Xg = tx*8 + x, Yg = ty*8 + y;
    const float* gq = g + (size_t)b*NB*PLP + (size_t)Xg*WP + Yg;
    float4 acc = {0.f, 0.f, 0.f, 0.f};
    for (int di = 0; di < KF; ++di) {
        const float* prow = pt + ((x+di)*18 + y)*LSTR + 4*w;
        const float* grow = gq + (size_t)di*KF*PLP;
        #pragma unroll
        for (int dj = 0; dj < KF; ++dj) {
            float gv = grow[(size_t)dj*PLP];
            float4 q = *(const float4*)(prow + dj*LSTR);
            acc.x = fmaf(gv, q.x, acc.x);
            acc.y = fmaf(gv, q.y, acc.y);
            acc.z = fmaf(gv, q.z, acc.z);
            acc.w = fmaf(gv, q.w, acc.w);
        }
    }
    int cb = 4*w;
    float* mb = msg + (size_t)b*CC*PLP + (size_t)Xg*WP + Yg;
    float av[4] = {acc.x, acc.y, acc.z, acc.w};
    #pragma unroll
    for (int k = 0; k < 4; ++k)
        if (cb + k < CC) mb[(size_t)(cb+k)*PLP] = av[k];
}

// bilinear 4x upsample of msg + 0.8*lg + 0.2*mu; iters 0..3: softmax + 4x4
// pool -> packed p; last iter: write fp32 pred. 2 pixels per thread.
// grid (16, 32, BB): block covers 16 rows x 32 cols.
__global__ __launch_bounds__(256) void combine_k(const float* __restrict__ msg,
                                                 const float* __restrict__ unary,
                                                 const float* __restrict__ weight,
                                                 float* __restrict__ pnew,
                                                 float* __restrict__ pred,
                                                 int last) {
    int b = blockIdx.z, tx = blockIdx.y, ty = blockIdx.x;
    int t = threadIdx.x;
    __shared__ float ms[CC][6][10];
    const float* mb = msg + (size_t)b*CC*PLP;
    for (int e = t; e < CC*60; e += 256) {
        int c = e / 60, rr = (e / 10) % 6, cl = e % 10;
        int gX = tx*4 - 1 + rr; gX = gX < 0 ? 0 : (gX > HP-1 ? HP-1 : gX);
        int gY = ty*8 - 1 + cl; gY = gY < 0 ? 0 : (gY > WP-1 ? WP-1 : gY);
        ms[c][rr][cl] = mb[(size_t)c*PLP + gX*WP + gY];
    }
    __syncthreads();
    int row = t >> 4, c2 = t & 15;
    int x = tx*16 + row, y = ty*32 + 2*c2;
    size_t base = (size_t)b*CC*PLF + (size_t)x*WW + y;
    // bilinear: fx per (x%4): {0.625, 0.875, 0.125, 0.375}
    int rs = row & 3, q = row >> 2;
    float fx = (rs == 0) ? 0.625f : (rs == 1) ? 0.875f : (rs == 2) ? 0.125f : 0.375f;
    int i0 = q + (rs >> 1);
    int cs0 = (2*c2) & 3;                    // 0 or 2; pixel pair shares j0
    int qc  = (2*c2) >> 2;
    float fya = (cs0 == 0) ? 0.625f : 0.125f;
    float fyb = (cs0 == 0) ? 0.875f : 0.375f;
    int j0 = qc + (cs0 >> 1);
    float gx0 = 1.f - fx;
    float wt = weight[0], uw = 1.f - wt;     // UNARY_WEIGHT = 1.0
    float va[CC], vb[CC];
    float ma = -1e30f, mbx = -1e30f;
    #pragma unroll
    for (int c = 0; c < CC; ++c) {
        float2 u = *(const float2*)(unary + base + (size_t)c*PLF);
        va[c] = u.x; vb[c] = u.y;
        ma = fmaxf(ma, u.x); mbx = fmaxf(mbx, u.y);
    }
    float sa = 0.f, sb = 0.f;
    #pragma unroll
    for (int c = 0; c < CC; ++c) { sa += expf(va[c]-ma); sb += expf(vb[c]-mbx); }
    float lsa = ma + logf(sa), lsb = mbx + logf(sb);
    #pragma unroll
    for (int c = 0; c < CC; ++c) {
        float m00 = ms[c][i0][j0],   m01 = ms[c][i0][j0+1];
        float m10 = ms[c][i0+1][j0], m11 = ms[c][i0+1][j0+1];
        float ca = gx0*m00 + fx*m10;         // column j0 blended in x
        float cb = gx0*m01 + fx*m11;         // column j0+1 blended in x
        float mua = (1.f-fya)*ca + fya*cb;
        float mub = (1.f-fyb)*ca + fyb*cb;
        va[c] = uw*(va[c]-lsa) + wt*mua;
        vb[c] = uw*(vb[c]-lsb) + wt*mub;
    }
    if (last) {
        #pragma unroll
        for (int c = 0; c < CC; ++c) {
            float2 o; o.x = va[c]; o.y = vb[c];
            *(float2*)(pred + base + (size_t)c*PLF) = o;
        }
    } else {
        float mma = -1e30f, mmb = -1e30f;
        #pragma unroll
        for (int c = 0; c < CC; ++c) { mma = fmaxf(mma, va[c]); mmb = fmaxf(mmb, vb[c]); }
        float ssa = 0.f, ssb = 0.f;
        #pragma unroll
        for (int c = 0; c < CC; ++c) {
            va[c] = expf(va[c]-mma); ssa += va[c];
            vb[c] = expf(vb[c]-mmb); ssb += vb[c];
        }
        float ia = 1.f/ssa, ib = 1.f/ssb;
        float out[PC];
        #pragma unroll
        for (int c = 0; c < PC; ++c) out[c] = 0.f;
        #pragma unroll
        for (int c = 0; c < CC; ++c) {
            float sm = va[c]*ia + vb[c]*ib;
            sm += __shfl_xor(sm, 1);
            sm += __shfl_xor(sm, 16);
            sm += __shfl_xor(sm, 32);
            out[c] = sm * (1.f/16.f);
        }
        int lane = t & 63;
        if ((lane & 49) == 0) {
            int X = tx*4 + (t >> 6), Y = ty*8 + (c2 >> 1);
            float4* dst = (float4*)(pnew + ((size_t)(b*HP + X)*WP + Y)*PC);
            const float4* src = (const float4*)out;
            dst[0]=src[0]; dst[1]=src[1]; dst[2]=src[2];
            dst[3]=src[3]; dst[4]=src[4]; dst[5]=src[5];
        }
    }
}

extern "C" void kernel_launch(void* const* d_in, const int* in_sizes, int n_in,
                              void* d_out, int out_size, void* d_ws, size_t ws_size,
                              hipStream_t stream) {
    const float* unary      = (const float*)d_in[0];
    const float* img        = (const float*)d_in[1];
    const float* pos_sdims  = (const float*)d_in[2];
    const float* col_schan  = (const float*)d_in[3];
    const float* pos_compat = (const float*)d_in[4];
    const float* col_compat = (const float*)d_in[5];
    const float* weight     = (const float*)d_in[6];
    float* pred = (float*)d_out;
    float* ws   = (float*)d_ws;

    size_t o = 0;
    float* cf  = ws + o;  o += (size_t)BB*3*PLP;     // 0.4 MB
    float* g   = ws + o;  o += (size_t)BB*NB*PLP;    // 15.9 MB
    float* msg = ws + o;  o += (size_t)BB*CC*PLP;    // 2.75 MB
    float* pA  = ws + o;  o += (size_t)BB*PLP*PC;    // 3.1 MB packed
    float* pB  = ws + o;
    float* pbuf[2] = {pA, pB};

    const int TB = 256;
    hipLaunchKernelGGL(pool_img_k, dim3((BB*3*PLP+TB-1)/TB), dim3(TB), 0, stream,
                       img, col_schan, cf);
    hipLaunchKernelGGL(gauss_k, dim3((BB*NB*PLP+TB-1)/TB), dim3(TB), 0, stream,
                       cf, pos_sdims, pos_compat, col_compat, g);
    hipLaunchKernelGGL(init_p_k, dim3(16, 32, BB), dim3(256), 0, stream,
                       unary, pA);
    for (int it = 0; it < NITER; ++it) {
        hipLaunchKernelGGL(msg_k, dim3(16, 16, BB), dim3(384), 0, stream,
                           g, pbuf[it & 1], msg);
        hipLaunchKernelGGL(combine_k, dim3(16, 32, BB), dim3(256), 0, stream,
                           msg, unary, weight, pbuf[(it + 1) & 1],
                           pred, (it == NITER-1) ? 1 : 0);
    }
}

// Round 2
// 1068.224 us; speedup vs baseline: 1.1923x; 1.1923x over previous
//
#include <hip/hip_runtime.h>
#include <cmath>

// GaussCRF on MI355X — round 9.
// B=2, C=21, H=W=512, blur=4 -> h=w=128, K=11 (121 shifts), 5 iterations.
//
// r8 post-mortem: channel-splitting msg across 6 waves replicated the
// scattered g gathers 6x; waves drift, lines re-fetched (FETCH 232 MB,
// WRITE 361 MB, 2.7 TB/s for 227 us). g traffic is the scarce resource.
// r9: g is staged ONCE per block into LDS and shared by all 6 waves.
//  * gauss_k now writes g block-tiled [b][tX][tY][ij][8x8] -> msg_k's g
//    slice is one contiguous 31 KB stream (line-exact, fully coalesced).
//  * p halo in LDS goes k-major float4 with row stride 19 (odd in float4
//    units -> the 8 x-segments of a wave b128 start at 8 distinct
//    bank-quads -> conflict-free; old 28-float stride was 8-way).
//  * inner loop per tap: ds_read_b32 (g, 2/bank = free) + ds_read_b128
//    (conflict-free) + 4 FMA. Same tap & channel order -> bit-identical.
//  * LDS 63.8 KB -> 2 blocks/CU, 12 waves/CU.

#define BB 2
#define CC 21
#define HH 512
#define WW 512
#define HP 128
#define WP 128
#define KF 11
#define SPAN 5
#define NB 121
#define NITER 5
#define PLF (HH*WW)
#define PLP (HP*WP)
#define PC 24      // packed channel stride (floats), 96 B = 6 x float4
#define PSTR 19    // p-halo LDS row stride in float4 units (odd -> no conflicts)

__global__ void pool_img_k(const float* __restrict__ img,
                           const float* __restrict__ col_schan,
                           float* __restrict__ cf) {
    int idx = blockIdx.x * blockDim.x + threadIdx.x;
    if (idx >= BB*3*PLP) return;
    int Y  = idx & (WP-1);
    int X  = (idx >> 7) & (HP-1);
    int bc = idx >> 14;
    const float* base = img + ((size_t)bc*HH + X*4)*WW + Y*4;
    float s = 0.f;
    #pragma unroll
    for (int i = 0; i < 4; ++i)
        #pragma unroll
        for (int j = 0; j < 4; ++j)
            s += base[i*WW + j];
    cf[idx] = s * (1.f/16.f) * col_schan[0];
}

// g block-tiled: g[((b*16+tX)*16+tY)*121*64 + ij*64 + pos], pos = 8x8 tile.
// grid (31, 512): blockIdx.y = tile, 256 thr cover 7744 elements.
__global__ void gauss_k(const float* __restrict__ cf,
                        const float* __restrict__ pos_sdims,
                        const float* __restrict__ pos_compat,
                        const float* __restrict__ col_compat,
                        float* __restrict__ g) {
    int tile = blockIdx.y;
    int e = blockIdx.x * blockDim.x + threadIdx.x;
    if (e >= NB*64) return;
    int pos = e & 63;
    int ij  = e >> 6;
    int tY = tile & 15, tX = (tile >> 4) & 15, b = tile >> 8;
    int X = tX*8 + (pos >> 3), Y = tY*8 + (pos & 7);
    int di = ij / KF - SPAN;
    int dj = ij % KF - SPAN;
    int Xn = X + di, Yn = Y + dj;
    float val = 0.f;
    if (Xn >= 0 && Xn < HP && Yn >= 0 && Yn < WP) {
        const float* cb = cf + (size_t)b*3*PLP;
        int o0 = X*WP + Y, o = Xn*WP + Yn;
        float d0 = cb[o]         - cb[o0];
        float d1 = cb[PLP + o]   - cb[PLP + o0];
        float d2 = cb[2*PLP + o] - cb[2*PLP + o0];
        float cd2 = d0*d0 + d1*d1 + d2*d2;
        float ps  = 4.f * pos_sdims[0];
        float pd2 = ps*ps * (float)(di*di + dj*dj);
        val = pos_compat[0] * expf(-0.5f*pd2) + col_compat[0] * expf(-0.5f*cd2);
    }
    g[(size_t)tile*NB*64 + e] = val;
}

// p0 = 4x4 pool of log_softmax(unary), packed fp32 [b][X][Y][24].
// grid (16, 32, BB): block covers 16 rows x 32 cols of full-res pixels.
__global__ __launch_bounds__(256) void init_p_k(const float* __restrict__ unary,
                                                float* __restrict__ p) {
    int b = blockIdx.z, tx = blockIdx.y, ty = blockIdx.x;
    int t = threadIdx.x;
    int row = t >> 4, c2 = t & 15;
    int x = tx*16 + row, y = ty*32 + 2*c2;
    size_t base = (size_t)b*CC*PLF + (size_t)x*WW + y;
    float va[CC], vb[CC];
    float ma = -1e30f, mb = -1e30f;
    #pragma unroll
    for (int c = 0; c < CC; ++c) {
        float2 u = *(const float2*)(unary + base + (size_t)c*PLF);
        va[c] = u.x; vb[c] = u.y;
        ma = fmaxf(ma, u.x); mb = fmaxf(mb, u.y);
    }
    float sa = 0.f, sb = 0.f;
    #pragma unroll
    for (int c = 0; c < CC; ++c) { sa += expf(va[c]-ma); sb += expf(vb[c]-mb); }
    float lsa = ma + logf(sa), lsb = mb + logf(sb);
    float out[PC];
    #pragma unroll
    for (int c = 0; c < PC; ++c) out[c] = 0.f;
    #pragma unroll
    for (int c = 0; c < CC; ++c) {
        float sm = (va[c]-lsa) + (vb[c]-lsb);
        sm += __shfl_xor(sm, 1);
        sm += __shfl_xor(sm, 16);
        sm += __shfl_xor(sm, 32);
        out[c] = sm * (1.f/16.f);
    }
    int lane = t & 63;
    if ((lane & 49) == 0) {                  // bits {0,4,5} == 0
        int X = tx*4 + (t >> 6), Y = ty*8 + (c2 >> 1);
        float4* dst = (float4*)(p + ((size_t)(b*HP + X)*WP + Y)*PC);
        const float4* src = (const float4*)out;
        dst[0]=src[0]; dst[1]=src[1]; dst[2]=src[2];
        dst[3]=src[3]; dst[4]=src[4]; dst[5]=src[5];
    }
}

// msg[b,c,X,Y] = sum_ij g[b,ij,X,Y] * p_packed[b,X+di-5,Y+dj-5,c]
// block = 384 thr = 6 waves; wave w owns channel quad 4w, lane = position.
// g tile (31 KB) staged once into LDS (coalesced, tiled layout); p halo
// staged k-major stride-19 float4 (conflict-free b128 reads).
__global__ __launch_bounds__(384) void msg_k(const float* __restrict__ g,
                                             const float* __restrict__ p,
                                             float* __restrict__ msg) {
    int b = blockIdx.z, tx = blockIdx.y, ty = blockIdx.x;
    int t = threadIdx.x;
    __shared__ __align__(16) float4 pt4[6][18*PSTR];   // 32.8 KB
    __shared__ __align__(16) float  gl[NB*64];         // 31.0 KB
    // stage g tile: 1936 float4, fully coalesced both sides
    const float4* gt = (const float4*)(g + (size_t)((b*16 + tx)*16 + ty)*NB*64);
    float4* gl4 = (float4*)gl;
    for (int e = t; e < NB*16; e += 384) gl4[e] = gt[e];
    // stage p halo
    int X0 = tx*8 - SPAN, Y0 = ty*8 - SPAN;
    const float4* pg = (const float4*)(p + (size_t)b*PLP*PC);
    for (int e = t; e < 18*18*6; e += 384) {
        int pos = e / 6, k = e % 6;
        int r = pos / 18, cl = pos % 18;
        int gX = X0 + r, gY = Y0 + cl;
        float4 v = {0.f,0.f,0.f,0.f};
        if (gX >= 0 && gX < HP && gY >= 0 && gY < WP)
            v = pg[(size_t)(gX*WP + gY)*6 + k];
        pt4[k][r*PSTR + cl] = v;
    }
    __syncthreads();
    int w = t >> 6, lane = t & 63;
    int x = lane >> 3, y = lane & 7;
    const float* gr = gl + lane;
    float4 acc = {0.f, 0.f, 0.f, 0.f};
    for (int di = 0; di < KF; ++di) {
        const float4* prow = &pt4[w][(x+di)*PSTR + y];
        const float* gtap = gr + ((size_t)di*KF << 6);
        #pragma unroll
        for (int dj = 0; dj < KF; ++dj) {
            float gv = gtap[dj << 6];
            float4 q = prow[dj];
            acc.x = fmaf(gv, q.x, acc.x);
            acc.y = fmaf(gv, q.y, acc.y);
            acc.z = fmaf(gv, q.z, acc.z);
            acc.w = fmaf(gv, q.w, acc.w);
        }
    }
    int Xg = tx*8 + x, Yg = ty*8 + y;
    int cb = 4*w;
    float* mb = msg + (size_t)b*CC*PLP + (size_t)Xg*WP + Yg;
    float av[4] = {acc.x, acc.y, acc.z, acc.w};
    #pragma unroll
    for (int k = 0; k < 4; ++k)
        if (cb + k < CC) mb[(size_t)(cb+k)*PLP] = av[k];
}

// bilinear 4x upsample of msg + 0.8*lg + 0.2*mu; iters 0..3: softmax + 4x4
// pool -> packed p; last iter: write fp32 pred. 2 pixels per thread.
// grid (16, 32, BB): block covers 16 rows x 32 cols.
__global__ __launch_bounds__(256) void combine_k(const float* __restrict__ msg,
                                                 const float* __restrict__ unary,
                                                 const float* __restrict__ weight,
                                                 float* __restrict__ pnew,
                                                 float* __restrict__ pred,
                                                 int last) {
    int b = blockIdx.z, tx = blockIdx.y, ty = blockIdx.x;
    int t = threadIdx.x;
    __shared__ float ms[CC][6][10];
    const float* mb = msg + (size_t)b*CC*PLP;
    for (int e = t; e < CC*60; e += 256) {
        int c = e / 60, rr = (e / 10) % 6, cl = e % 10;
        int gX = tx*4 - 1 + rr; gX = gX < 0 ? 0 : (gX > HP-1 ? HP-1 : gX);
        int gY = ty*8 - 1 + cl; gY = gY < 0 ? 0 : (gY > WP-1 ? WP-1 : gY);
        ms[c][rr][cl] = mb[(size_t)c*PLP + gX*WP + gY];
    }
    __syncthreads();
    int row = t >> 4, c2 = t & 15;
    int x = tx*16 + row, y = ty*32 + 2*c2;
    size_t base = (size_t)b*CC*PLF + (size_t)x*WW + y;
    // bilinear: fx per (x%4): {0.625, 0.875, 0.125, 0.375}
    int rs = row & 3, q = row >> 2;
    float fx = (rs == 0) ? 0.625f : (rs == 1) ? 0.875f : (rs == 2) ? 0.125f : 0.375f;
    int i0 = q + (rs >> 1);
    int cs0 = (2*c2) & 3;                    // 0 or 2; pixel pair shares j0
    int qc  = (2*c2) >> 2;
    float fya = (cs0 == 0) ? 0.625f : 0.125f;
    float fyb = (cs0 == 0) ? 0.875f : 0.375f;
    int j0 = qc + (cs0 >> 1);
    float gx0 = 1.f - fx;
    float wt = weight[0], uw = 1.f - wt;     // UNARY_WEIGHT = 1.0
    float va[CC], vb[CC];
    float ma = -1e30f, mbx = -1e30f;
    #pragma unroll
    for (int c = 0; c < CC; ++c) {
        float2 u = *(const float2*)(unary + base + (size_t)c*PLF);
        va[c] = u.x; vb[c] = u.y;
        ma = fmaxf(ma, u.x); mbx = fmaxf(mbx, u.y);
    }
    float sa = 0.f, sb = 0.f;
    #pragma unroll
    for (int c = 0; c < CC; ++c) { sa += expf(va[c]-ma); sb += expf(vb[c]-mbx); }
    float lsa = ma + logf(sa), lsb = mbx + logf(sb);
    #pragma unroll
    for (int c = 0; c < CC; ++c) {
        float m00 = ms[c][i0][j0],   m01 = ms[c][i0][j0+1];
        float m10 = ms[c][i0+1][j0], m11 = ms[c][i0+1][j0+1];
        float ca = gx0*m00 + fx*m10;         // column j0 blended in x
        float cb = gx0*m01 + fx*m11;         // column j0+1 blended in x
        float mua = (1.f-fya)*ca + fya*cb;
        float mub = (1.f-fyb)*ca + fyb*cb;
        va[c] = uw*(va[c]-lsa) + wt*mua;
        vb[c] = uw*(vb[c]-lsb) + wt*mub;
    }
    if (last) {
        #pragma unroll
        for (int c = 0; c < CC; ++c) {
            float2 o; o.x = va[c]; o.y = vb[c];
            *(float2*)(pred + base + (size_t)c*PLF) = o;
        }
    } else {
        float mma = -1e30f, mmb = -1e30f;
        #pragma unroll
        for (int c = 0; c < CC; ++c) { mma = fmaxf(mma, va[c]); mmb = fmaxf(mmb, vb[c]); }
        float ssa = 0.f, ssb = 0.f;
        #pragma unroll
        for (int c = 0; c < CC; ++c) {
            va[c] = expf(va[c]-mma); ssa += va[c];
            vb[c] = expf(vb[c]-mmb); ssb += vb[c];
        }
        float ia = 1.f/ssa, ib = 1.f/ssb;
        float out[PC];
        #pragma unroll
        for (int c = 0; c < PC; ++c) out[c] = 0.f;
        #pragma unroll
        for (int c = 0; c < CC; ++c) {
            float sm = va[c]*ia + vb[c]*ib;
            sm += __shfl_xor(sm, 1);
            sm += __shfl_xor(sm, 16);
            sm += __shfl_xor(sm, 32);
            out[c] = sm * (1.f/16.f);
        }
        int lane = t & 63;
        if ((lane & 49) == 0) {
            int X = tx*4 + (t >> 6), Y = ty*8 + (c2 >> 1);
            float4* dst = (float4*)(pnew + ((size_t)(b*HP + X)*WP + Y)*PC);
            const float4* src = (const float4*)out;
            dst[0]=src[0]; dst[1]=src[1]; dst[2]=src[2];
            dst[3]=src[3]; dst[4]=src[4]; dst[5]=src[5];
        }
    }
}

extern "C" void kernel_launch(void* const* d_in, const int* in_sizes, int n_in,
                              void* d_out, int out_size, void* d_ws, size_t ws_size,
                              hipStream_t stream) {
    const float* unary      = (const float*)d_in[0];
    const float* img        = (const float*)d_in[1];
    const float* pos_sdims  = (const float*)d_in[2];
    const float* col_schan  = (const float*)d_in[3];
    const float* pos_compat = (const float*)d_in[4];
    const float* col_compat = (const float*)d_in[5];
    const float* weight     = (const float*)d_in[6];
    float* pred = (float*)d_out;
    float* ws   = (float*)d_ws;

    size_t o = 0;
    float* cf  = ws + o;  o += (size_t)BB*3*PLP;     // 0.4 MB
    float* g   = ws + o;  o += (size_t)BB*NB*PLP;    // 15.9 MB (tiled)
    float* msg = ws + o;  o += (size_t)BB*CC*PLP;    // 2.75 MB
    float* pA  = ws + o;  o += (size_t)BB*PLP*PC;    // 3.1 MB packed
    float* pB  = ws + o;
    float* pbuf[2] = {pA, pB};

    const int TB = 256;
    hipLaunchKernelGGL(pool_img_k, dim3((BB*3*PLP+TB-1)/TB), dim3(TB), 0, stream,
                       img, col_schan, cf);
    hipLaunchKernelGGL(gauss_k, dim3((NB*64+TB-1)/TB, 512), dim3(TB), 0, stream,
                       cf, pos_sdims, pos_compat, col_compat, g);
    hipLaunchKernelGGL(init_p_k, dim3(16, 32, BB), dim3(256), 0, stream,
                       unary, pA);
    for (int it = 0; it < NITER; ++it) {
        hipLaunchKernelGGL(msg_k, dim3(16, 16, BB), dim3(384), 0, stream,
                           g, pbuf[it & 1], msg);
        hipLaunchKernelGGL(combine_k, dim3(16, 32, BB), dim3(256), 0, stream,
                           msg, unary, weight, pbuf[(it + 1) & 1],
                           pred, (it == NITER-1) ? 1 : 0);
    }
}

// Round 3
// 271.189 us; speedup vs baseline: 4.6963x; 3.9390x over previous
//
#include <hip/hip_runtime.h>
#include <cmath>

// GaussCRF on MI355X — round 10.
// B=2, C=21, H=W=512, blur=4 -> h=w=128, K=11 (121 shifts), 5 iterations.
//
// r8/r9 post-mortem: 6-wave channel-split msg_k generated ~470 MB of REAL
// HBM traffic per dispatch (FETCH 194 + WRITE 274 MB ~= 6x the per-block
// staging volume); 10 dispatches x 470 MB / 6.3 TB/s ~= the +750 us
// regression vs r7. The single-wave r7 microstructure had none of it
// (~19 us real). Bank-conflict counter was a red herring (b128 intrinsic
// cycles; r7's stride-28 layout is provably balanced, 8 lanes/bank-quad).
//
// r10: r7 per-wave microstructure restored (channel-major, stride-28 halo,
// bit-identical per-tap arithmetic), occupancy via TAP-SPLIT:
//  * 256-thr blocks, 4 waves; wave w does di rows {0-2,3-5,6-8,9-10}.
//  * waves 1-3 write 21 partials to stride-25 LDS (conflict-free);
//    wave 0 adds in fixed order (w1,w2,w3) and stores -> deterministic,
//    ~1e-7 regroup perturbation only.
//  * g stays in r9's block-tiled layout: per tap the wave reads 64
//    contiguous floats (2 cache lines) instead of 8x32B gather; taps are
//    disjoint across waves -> g traffic = 15.9 MB exact, no replication.
//  * LDS 55.5 KB -> 2 blocks/CU = 8 waves/CU (r7: 2 waves/CU).

#define BB 2
#define CC 21
#define HH 512
#define WW 512
#define HP 128
#define WP 128
#define KF 11
#define SPAN 5
#define NB 121
#define NITER 5
#define PLF (HH*WW)
#define PLP (HP*WP)
#define PC 24      // packed channel stride (floats), 96 B = 6 x float4
#define LSTR 28    // halo LDS stride in floats (r7 layout, balanced banks)
#define RSTR 25    // reduce-buffer lane stride (odd -> conflict-free)

__global__ void pool_img_k(const float* __restrict__ img,
                           const float* __restrict__ col_schan,
                           float* __restrict__ cf) {
    int idx = blockIdx.x * blockDim.x + threadIdx.x;
    if (idx >= BB*3*PLP) return;
    int Y  = idx & (WP-1);
    int X  = (idx >> 7) & (HP-1);
    int bc = idx >> 14;
    const float* base = img + ((size_t)bc*HH + X*4)*WW + Y*4;
    float s = 0.f;
    #pragma unroll
    for (int i = 0; i < 4; ++i)
        #pragma unroll
        for (int j = 0; j < 4; ++j)
            s += base[i*WW + j];
    cf[idx] = s * (1.f/16.f) * col_schan[0];
}

// g block-tiled: g[((b*16+tX)*16+tY)*121*64 + ij*64 + pos], pos = 8x8 tile.
__global__ void gauss_k(const float* __restrict__ cf,
                        const float* __restrict__ pos_sdims,
                        const float* __restrict__ pos_compat,
                        const float* __restrict__ col_compat,
                        float* __restrict__ g) {
    int tile = blockIdx.y;
    int e = blockIdx.x * blockDim.x + threadIdx.x;
    if (e >= NB*64) return;
    int pos = e & 63;
    int ij  = e >> 6;
    int tY = tile & 15, tX = (tile >> 4) & 15, b = tile >> 8;
    int X = tX*8 + (pos >> 3), Y = tY*8 + (pos & 7);
    int di = ij / KF - SPAN;
    int dj = ij % KF - SPAN;
    int Xn = X + di, Yn = Y + dj;
    float val = 0.f;
    if (Xn >= 0 && Xn < HP && Yn >= 0 && Yn < WP) {
        const float* cb = cf + (size_t)b*3*PLP;
        int o0 = X*WP + Y, o = Xn*WP + Yn;
        float d0 = cb[o]         - cb[o0];
        float d1 = cb[PLP + o]   - cb[PLP + o0];
        float d2 = cb[2*PLP + o] - cb[2*PLP + o0];
        float cd2 = d0*d0 + d1*d1 + d2*d2;
        float ps  = 4.f * pos_sdims[0];
        float pd2 = ps*ps * (float)(di*di + dj*dj);
        val = pos_compat[0] * expf(-0.5f*pd2) + col_compat[0] * expf(-0.5f*cd2);
    }
    g[(size_t)tile*NB*64 + e] = val;
}

// p0 = 4x4 pool of log_softmax(unary), packed fp32 [b][X][Y][24].
__global__ __launch_bounds__(256) void init_p_k(const float* __restrict__ unary,
                                                float* __restrict__ p) {
    int b = blockIdx.z, tx = blockIdx.y, ty = blockIdx.x;
    int t = threadIdx.x;
    int row = t >> 4, c2 = t & 15;
    int x = tx*16 + row, y = ty*32 + 2*c2;
    size_t base = (size_t)b*CC*PLF + (size_t)x*WW + y;
    float va[CC], vb[CC];
    float ma = -1e30f, mb = -1e30f;
    #pragma unroll
    for (int c = 0; c < CC; ++c) {
        float2 u = *(const float2*)(unary + base + (size_t)c*PLF);
        va[c] = u.x; vb[c] = u.y;
        ma = fmaxf(ma, u.x); mb = fmaxf(mb, u.y);
    }
    float sa = 0.f, sb = 0.f;
    #pragma unroll
    for (int c = 0; c < CC; ++c) { sa += expf(va[c]-ma); sb += expf(vb[c]-mb); }
    float lsa = ma + logf(sa), lsb = mb + logf(sb);
    float out[PC];
    #pragma unroll
    for (int c = 0; c < PC; ++c) out[c] = 0.f;
    #pragma unroll
    for (int c = 0; c < CC; ++c) {
        float sm = (va[c]-lsa) + (vb[c]-lsb);
        sm += __shfl_xor(sm, 1);
        sm += __shfl_xor(sm, 16);
        sm += __shfl_xor(sm, 32);
        out[c] = sm * (1.f/16.f);
    }
    int lane = t & 63;
    if ((lane & 49) == 0) {                  // bits {0,4,5} == 0
        int X = tx*4 + (t >> 6), Y = ty*8 + (c2 >> 1);
        float4* dst = (float4*)(p + ((size_t)(b*HP + X)*WP + Y)*PC);
        const float4* src = (const float4*)out;
        dst[0]=src[0]; dst[1]=src[1]; dst[2]=src[2];
        dst[3]=src[3]; dst[4]=src[4]; dst[5]=src[5];
    }
}

// msg[b,c,X,Y] = sum_ij g[b,ij,X,Y] * p_packed[b,X+di-5,Y+dj-5,c]
// 256 thr = 4 waves, all channel-major (r7 microstructure); wave w owns
// di rows {0-2, 3-5, 6-8, 9-10}. Halo in r7's stride-28 layout; partials
// reduced through stride-25 LDS in fixed order.
__global__ __launch_bounds__(256) void msg_k(const float* __restrict__ g,
                                             const float* __restrict__ p,
                                             float* __restrict__ msg) {
    int b = blockIdx.z, tx = blockIdx.y, ty = blockIdx.x;
    int t = threadIdx.x;
    __shared__ __align__(16) float pt[18*18*LSTR];     // 36.3 KB
    __shared__ float rbuf[3][64][RSTR];                // 19.2 KB
    int X0 = tx*8 - SPAN, Y0 = ty*8 - SPAN;
    const float4* pg = (const float4*)(p + (size_t)b*PLP*PC);
    for (int e = t; e < 18*18*6; e += 256) {
        int pos = e / 6, k = e % 6;
        int r = pos / 18, cl = pos % 18;
        int gX = X0 + r, gY = Y0 + cl;
        float4 v = {0.f,0.f,0.f,0.f};
        if (gX >= 0 && gX < HP && gY >= 0 && gY < WP)
            v = pg[(size_t)(gX*WP + gY)*6 + k];
        *(float4*)(pt + pos*LSTR + k*4) = v;
    }
    __syncthreads();
    int w = t >> 6, lane = t & 63;
    int x = lane >> 3, y = lane & 7;
    const float* gt = g + (size_t)((b*16 + tx)*16 + ty)*NB*64 + lane;
    int d0 = w*3, d1 = (w == 3) ? KF : w*3 + 3;        // {0-2,3-5,6-8,9-10}
    float acc[CC];
    #pragma unroll
    for (int c = 0; c < CC; ++c) acc[c] = 0.f;
    for (int di = d0; di < d1; ++di) {
        const float* prow = pt + ((x+di)*18 + y)*LSTR;
        const float* grow = gt + (size_t)(di*KF)*64;
        #pragma unroll
        for (int dj = 0; dj < KF; ++dj) {
            float gv = grow[(size_t)dj*64];
            const float4* sp = (const float4*)(prow + dj*LSTR);
            float4 q0 = sp[0], q1 = sp[1], q2 = sp[2];
            float4 q3 = sp[3], q4 = sp[4], q5 = sp[5];
            acc[0]  = fmaf(gv, q0.x, acc[0]);  acc[1]  = fmaf(gv, q0.y, acc[1]);
            acc[2]  = fmaf(gv, q0.z, acc[2]);  acc[3]  = fmaf(gv, q0.w, acc[3]);
            acc[4]  = fmaf(gv, q1.x, acc[4]);  acc[5]  = fmaf(gv, q1.y, acc[5]);
            acc[6]  = fmaf(gv, q1.z, acc[6]);  acc[7]  = fmaf(gv, q1.w, acc[7]);
            acc[8]  = fmaf(gv, q2.x, acc[8]);  acc[9]  = fmaf(gv, q2.y, acc[9]);
            acc[10] = fmaf(gv, q2.z, acc[10]); acc[11] = fmaf(gv, q2.w, acc[11]);
            acc[12] = fmaf(gv, q3.x, acc[12]); acc[13] = fmaf(gv, q3.y, acc[13]);
            acc[14] = fmaf(gv, q3.z, acc[14]); acc[15] = fmaf(gv, q3.w, acc[15]);
            acc[16] = fmaf(gv, q4.x, acc[16]); acc[17] = fmaf(gv, q4.y, acc[17]);
            acc[18] = fmaf(gv, q4.z, acc[18]); acc[19] = fmaf(gv, q4.w, acc[19]);
            acc[20] = fmaf(gv, q5.x, acc[20]);
        }
    }
    if (w > 0) {
        #pragma unroll
        for (int c = 0; c < CC; ++c) rbuf[w-1][lane][c] = acc[c];
    }
    __syncthreads();
    if (w == 0) {
        int Xg = tx*8 + x, Yg = ty*8 + y;
        float* mb = msg + (size_t)b*CC*PLP + (size_t)Xg*WP + Yg;
        #pragma unroll
        for (int c = 0; c < CC; ++c) {
            float s = ((acc[c] + rbuf[0][lane][c]) + rbuf[1][lane][c])
                      + rbuf[2][lane][c];
            mb[(size_t)c*PLP] = s;
        }
    }
}

// bilinear 4x upsample of msg + 0.8*lg + 0.2*mu; iters 0..3: softmax + 4x4
// pool -> packed p; last iter: write fp32 pred. 2 pixels per thread.
__global__ __launch_bounds__(256) void combine_k(const float* __restrict__ msg,
                                                 const float* __restrict__ unary,
                                                 const float* __restrict__ weight,
                                                 float* __restrict__ pnew,
                                                 float* __restrict__ pred,
                                                 int last) {
    int b = blockIdx.z, tx = blockIdx.y, ty = blockIdx.x;
    int t = threadIdx.x;
    __shared__ float ms[CC][6][10];
    const float* mb = msg + (size_t)b*CC*PLP;
    for (int e = t; e < CC*60; e += 256) {
        int c = e / 60, rr = (e / 10) % 6, cl = e % 10;
        int gX = tx*4 - 1 + rr; gX = gX < 0 ? 0 : (gX > HP-1 ? HP-1 : gX);
        int gY = ty*8 - 1 + cl; gY = gY < 0 ? 0 : (gY > WP-1 ? WP-1 : gY);
        ms[c][rr][cl] = mb[(size_t)c*PLP + gX*WP + gY];
    }
    __syncthreads();
    int row = t >> 4, c2 = t & 15;
    int x = tx*16 + row, y = ty*32 + 2*c2;
    size_t base = (size_t)b*CC*PLF + (size_t)x*WW + y;
    // bilinear: fx per (x%4): {0.625, 0.875, 0.125, 0.375}
    int rs = row & 3, q = row >> 2;
    float fx = (rs == 0) ? 0.625f : (rs == 1) ? 0.875f : (rs == 2) ? 0.125f : 0.375f;
    int i0 = q + (rs >> 1);
    int cs0 = (2*c2) & 3;                    // 0 or 2; pixel pair shares j0
    int qc  = (2*c2) >> 2;
    float fya = (cs0 == 0) ? 0.625f : 0.125f;
    float fyb = (cs0 == 0) ? 0.875f : 0.375f;
    int j0 = qc + (cs0 >> 1);
    float gx0 = 1.f - fx;
    float wt = weight[0], uw = 1.f - wt;     // UNARY_WEIGHT = 1.0
    float va[CC], vb[CC];
    float ma = -1e30f, mbx = -1e30f;
    #pragma unroll
    for (int c = 0; c < CC; ++c) {
        float2 u = *(const float2*)(unary + base + (size_t)c*PLF);
        va[c] = u.x; vb[c] = u.y;
        ma = fmaxf(ma, u.x); mbx = fmaxf(mbx, u.y);
    }
    float sa = 0.f, sb = 0.f;
    #pragma unroll
    for (int c = 0; c < CC; ++c) { sa += expf(va[c]-ma); sb += expf(vb[c]-mbx); }
    float lsa = ma + logf(sa), lsb = mbx + logf(sb);
    #pragma unroll
    for (int c = 0; c < CC; ++c) {
        float m00 = ms[c][i0][j0],   m01 = ms[c][i0][j0+1];
        float m10 = ms[c][i0+1][j0], m11 = ms[c][i0+1][j0+1];
        float ca = gx0*m00 + fx*m10;         // column j0 blended in x
        float cb = gx0*m01 + fx*m11;         // column j0+1 blended in x
        float mua = (1.f-fya)*ca + fya*cb;
        float mub = (1.f-fyb)*ca + fyb*cb;
        va[c] = uw*(va[c]-lsa) + wt*mua;
        vb[c] = uw*(vb[c]-lsb) + wt*mub;
    }
    if (last) {
        #pragma unroll
        for (int c = 0; c < CC; ++c) {
            float2 o; o.x = va[c]; o.y = vb[c];
            *(float2*)(pred + base + (size_t)c*PLF) = o;
        }
    } else {
        float mma = -1e30f, mmb = -1e30f;
        #pragma unroll
        for (int c = 0; c < CC; ++c) { mma = fmaxf(mma, va[c]); mmb = fmaxf(mmb, vb[c]); }
        float ssa = 0.f, ssb = 0.f;
        #pragma unroll
        for (int c = 0; c < CC; ++c) {
            va[c] = expf(va[c]-mma); ssa += va[c];
            vb[c] = expf(vb[c]-mmb); ssb += vb[c];
        }
        float ia = 1.f/ssa, ib = 1.f/ssb;
        float out[PC];
        #pragma unroll
        for (int c = 0; c < PC; ++c) out[c] = 0.f;
        #pragma unroll
        for (int c = 0; c < CC; ++c) {
            float sm = va[c]*ia + vb[c]*ib;
            sm += __shfl_xor(sm, 1);
            sm += __shfl_xor(sm, 16);
            sm += __shfl_xor(sm, 32);
            out[c] = sm * (1.f/16.f);
        }
        int lane = t & 63;
        if ((lane & 49) == 0) {
            int X = tx*4 + (t >> 6), Y = ty*8 + (c2 >> 1);
            float4* dst = (float4*)(pnew + ((size_t)(b*HP + X)*WP + Y)*PC);
            const float4* src = (const float4*)out;
            dst[0]=src[0]; dst[1]=src[1]; dst[2]=src[2];
            dst[3]=src[3]; dst[4]=src[4]; dst[5]=src[5];
        }
    }
}

extern "C" void kernel_launch(void* const* d_in, const int* in_sizes, int n_in,
                              void* d_out, int out_size, void* d_ws, size_t ws_size,
                              hipStream_t stream) {
    const float* unary      = (const float*)d_in[0];
    const float* img        = (const float*)d_in[1];
    const float* pos_sdims  = (const float*)d_in[2];
    const float* col_schan  = (const float*)d_in[3];
    const float* pos_compat = (const float*)d_in[4];
    const float* col_compat = (const float*)d_in[5];
    const float* weight     = (const float*)d_in[6];
    float* pred = (float*)d_out;
    float* ws   = (float*)d_ws;

    size_t o = 0;
    float* cf  = ws + o;  o += (size_t)BB*3*PLP;     // 0.4 MB
    float* g   = ws + o;  o += (size_t)BB*NB*PLP;    // 15.9 MB (tiled)
    float* msg = ws + o;  o += (size_t)BB*CC*PLP;    // 2.75 MB
    float* pA  = ws + o;  o += (size_t)BB*PLP*PC;    // 3.1 MB packed
    float* pB  = ws + o;
    float* pbuf[2] = {pA, pB};

    const int TB = 256;
    hipLaunchKernelGGL(pool_img_k, dim3((BB*3*PLP+TB-1)/TB), dim3(TB), 0, stream,
                       img, col_schan, cf);
    hipLaunchKernelGGL(gauss_k, dim3((NB*64+TB-1)/TB, 512), dim3(TB), 0, stream,
                       cf, pos_sdims, pos_compat, col_compat, g);
    hipLaunchKernelGGL(init_p_k, dim3(16, 32, BB), dim3(256), 0, stream,
                       unary, pA);
    for (int it = 0; it < NITER; ++it) {
        hipLaunchKernelGGL(msg_k, dim3(16, 16, BB), dim3(256), 0, stream,
                           g, pbuf[it & 1], msg);
        hipLaunchKernelGGL(combine_k, dim3(16, 32, BB), dim3(256), 0, stream,
                           msg, unary, weight, pbuf[(it + 1) & 1],
                           pred, (it == NITER-1) ? 1 : 0);
    }
}